// Round 2
// baseline (698.842 us; speedup 1.0000x reference)
//
#include <hip/hip_runtime.h>

#define NRES 768
#define CPAIR 128
#define CMSA 256

// One wave64 per (i,j) pair. Lane l holds channels 2l, 2l+1 (float2 = 512B/wave,
// perfectly coalesced). Layernorm via 6-step shfl_xor butterfly, two-pass to
// match reference mean((x-mu)^2) exactly.
__global__ __launch_bounds__(256) void pair_kernel(
    const int* __restrict__ aatype,
    const int* __restrict__ residue_index,
    const int* __restrict__ asym_id,
    const int* __restrict__ entity_id,
    const int* __restrict__ sym_id,
    const float* __restrict__ prev_pos,
    const float* __restrict__ prev_pair,
    const float* __restrict__ w_dgram,
    const float* __restrict__ b_dgram,
    const float* __restrict__ g_pair,
    const float* __restrict__ bt_pair,
    const float* __restrict__ w_rel,
    const float* __restrict__ b_rel,
    float* __restrict__ out_pair)
{
    const int lane = threadIdx.x & 63;
    const int wid  = threadIdx.x >> 6;
    const int pidx = blockIdx.x * 4 + wid;   // grid sized exactly: 768*768/4 blocks
    const int i = pidx / NRES;
    const int j = pidx - i * NRES;

    // ---- wave-uniform scalar work: distogram bin + relative features ----
    const int ai = (aatype[i] == 7) ? 1 : 3;   // GLY -> CA(1) else CB(3)
    const int aj = (aatype[j] == 7) ? 1 : 3;
    const float* pi = prev_pos + ((long)i * 37 + ai) * 3;
    const float* pj = prev_pos + ((long)j * 37 + aj) * 3;
    const float dx = pi[0] - pj[0];
    const float dy = pi[1] - pj[1];
    const float dz = pi[2] - pj[2];
    const float d2 = dx * dx + dy * dy + dz * dz;

    int bin = -1;
    #pragma unroll
    for (int b = 0; b < 15; ++b) {
        const float lo = 3.25f + 1.25f * (float)b;   // exact multiples of 0.25
        const float l2 = lo * lo;
        const float hi = lo + 1.25f;
        const float u2 = (b == 14) ? 1e8f : hi * hi;
        if (d2 > l2 && d2 < u2) bin = b;             // strict, matches reference
    }

    const bool asame = asym_id[i] == asym_id[j];
    int off = residue_index[i] - residue_index[j] + 32;
    off = min(max(off, 0), 64);
    const int p = asame ? off : 65;                  // rel_pos one-hot index

    const bool esame = entity_id[i] == entity_id[j];
    int ch = sym_id[i] - sym_id[j] + 2;
    ch = min(max(ch, 0), 4);
    const int chi = esame ? ch : 5;                  // rel_chain one-hot index

    // ---- per-lane channel work ----
    const int c = lane * 2;
    const long base = ((long)i * NRES + j) * CPAIR + c;
    const float2 x = *(const float2*)(prev_pair + base);

    float s = x.x + x.y;
    #pragma unroll
    for (int m = 32; m >= 1; m >>= 1) s += __shfl_xor(s, m);
    const float mu = s * (1.0f / 128.0f);

    const float vx = x.x - mu;
    const float vy = x.y - mu;
    float v = vx * vx + vy * vy;
    #pragma unroll
    for (int m = 32; m >= 1; m >>= 1) v += __shfl_xor(v, m);
    const float rstd = rsqrtf(v * (1.0f / 128.0f) + 1e-5f);

    const float2 g  = *(const float2*)(g_pair  + c);
    const float2 bt = *(const float2*)(bt_pair + c);
    const float2 bd = *(const float2*)(b_dgram + c);
    const float2 br = *(const float2*)(b_rel   + c);
    const float2 wp = *(const float2*)(w_rel + (long)p * CPAIR + c);
    const float2 wc = *(const float2*)(w_rel + (long)(67 + chi) * CPAIR + c);

    float add_x = (bd.x + br.x) + (wp.x + wc.x);
    float add_y = (bd.y + br.y) + (wp.y + wc.y);
    if (esame) {
        const float2 we = *(const float2*)(w_rel + 66L * CPAIR + c);
        add_x += we.x;
        add_y += we.y;
    }
    if (bin >= 0) {
        const float2 wd = *(const float2*)(w_dgram + (long)bin * CPAIR + c);
        add_x += wd.x;
        add_y += wd.y;
    }

    float2 o;
    o.x = vx * rstd * g.x + bt.x + add_x;
    o.y = vy * rstd * g.y + bt.y + add_y;
    *(float2*)(out_pair + base) = o;
}

// One wave64 per residue row; lane l holds channels 4l..4l+3 (float4).
__global__ __launch_bounds__(256) void msa_kernel(
    const float* __restrict__ prev_msa,
    const float* __restrict__ g_msa,
    const float* __restrict__ bt_msa,
    float* __restrict__ out_msa)
{
    const int lane = threadIdx.x & 63;
    const int row = (int)((blockIdx.x * blockDim.x + threadIdx.x) >> 6);
    if (row >= NRES) return;

    const int c = lane * 4;
    const long base = (long)row * CMSA + c;
    const float4 x = *(const float4*)(prev_msa + base);

    float s = (x.x + x.y) + (x.z + x.w);
    #pragma unroll
    for (int m = 32; m >= 1; m >>= 1) s += __shfl_xor(s, m);
    const float mu = s * (1.0f / 256.0f);

    const float a0 = x.x - mu, a1 = x.y - mu, a2 = x.z - mu, a3 = x.w - mu;
    float v = (a0 * a0 + a1 * a1) + (a2 * a2 + a3 * a3);
    #pragma unroll
    for (int m = 32; m >= 1; m >>= 1) v += __shfl_xor(v, m);
    const float rstd = rsqrtf(v * (1.0f / 256.0f) + 1e-5f);

    const float4 g  = *(const float4*)(g_msa  + c);
    const float4 bt = *(const float4*)(bt_msa + c);
    float4 o;
    o.x = a0 * rstd * g.x + bt.x;
    o.y = a1 * rstd * g.y + bt.y;
    o.z = a2 * rstd * g.z + bt.z;
    o.w = a3 * rstd * g.w + bt.w;
    *(float4*)(out_msa + base) = o;
}

extern "C" void kernel_launch(void* const* d_in, const int* in_sizes, int n_in,
                              void* d_out, int out_size, void* d_ws, size_t ws_size,
                              hipStream_t stream) {
    const int*   aatype        = (const int*)d_in[0];
    const int*   residue_index = (const int*)d_in[1];
    const int*   asym_id       = (const int*)d_in[2];
    const int*   entity_id     = (const int*)d_in[3];
    const int*   sym_id        = (const int*)d_in[4];
    const float* prev_pos      = (const float*)d_in[5];
    const float* prev_pair     = (const float*)d_in[6];
    const float* prev_msa      = (const float*)d_in[7];
    const float* w_dgram       = (const float*)d_in[8];
    const float* b_dgram       = (const float*)d_in[9];
    const float* g_pair        = (const float*)d_in[10];
    const float* bt_pair       = (const float*)d_in[11];
    const float* g_msa         = (const float*)d_in[12];
    const float* bt_msa        = (const float*)d_in[13];
    const float* w_rel         = (const float*)d_in[14];
    const float* b_rel         = (const float*)d_in[15];

    float* out_msa  = (float*)d_out;                       // [768,256] first
    float* out_pair = out_msa + (long)NRES * CMSA;         // then [768,768,128]

    msa_kernel<<<(NRES * 64 + 255) / 256, 256, 0, stream>>>(
        prev_msa, g_msa, bt_msa, out_msa);

    pair_kernel<<<(NRES * NRES) / 4, 256, 0, stream>>>(
        aatype, residue_index, asym_id, entity_id, sym_id,
        prev_pos, prev_pair,
        w_dgram, b_dgram, g_pair, bt_pair, w_rel, b_rel,
        out_pair);
}